// Round 2
// baseline (808.632 us; speedup 1.0000x reference)
//
#include <hip/hip_runtime.h>

#define NN 10000      // nodes
#define NE 320000     // edges
#define HD 128        // h_dim
#define ED 16         // e_dim
#define HID 256       // hid_dim
#define NS 64         // n_step
#define KP 480        // padded K: [x 128 | cnt*x 128 | sum_xj 128 | sum_soh 64 | sum_ea 16 | cnt 1 | pad 15]

__device__ __forceinline__ float leaky(float v){ return v > 0.f ? v : 0.01f*v; }

// ---- CSR build ----
__global__ __launch_bounds__(256) void k_count(const int* __restrict__ ii, int* __restrict__ cnt){
  int e = blockIdx.x*256 + threadIdx.x;
  if (e < NE) atomicAdd(&cnt[ii[e]], 1);
}

__global__ __launch_bounds__(256) void k_scan(const int* __restrict__ cnt, int* __restrict__ row_ptr){
  __shared__ int s[256];
  int t = threadIdx.x;
  int running = 0;
  for (int base = 0; base < NN; base += 256){
    int v = (base+t < NN) ? cnt[base+t] : 0;
    s[t] = v; __syncthreads();
    int x = v;
    for (int off = 1; off < 256; off <<= 1){
      int add = (t >= off) ? s[t-off] : 0;
      __syncthreads();
      x += add; s[t] = x;
      __syncthreads();
    }
    if (base+t < NN) row_ptr[base+t] = running + x - v;
    int tot = s[255];
    __syncthreads();
    running += tot;
  }
  if (t == 0) row_ptr[NN] = running;
}

__global__ __launch_bounds__(256) void k_fill(const int* __restrict__ ii, const int* __restrict__ jj,
                                              const int* __restrict__ row_ptr, int* __restrict__ c2,
                                              int* __restrict__ sj, int* __restrict__ se){
  int e = blockIdx.x*256 + threadIdx.x;
  if (e < NE){
    int a = ii[e];
    int p = atomicAdd(&c2[a], 1);
    int idx = row_ptr[a] + p;
    sj[idx] = jj[e];
    se[idx] = e;
  }
}

// ---- combined weights: Wc[l][r][c], r<128: Wx_top; 128..463: Wm@Wx_bot; 464: bm@Wx_bot; pad 0 ----
__global__ __launch_bounds__(256) void k_wc(const float* __restrict__ Wm, const float* __restrict__ bm,
                                            const float* __restrict__ Wx, float* __restrict__ Wc){
  int t = blockIdx.x*256 + threadIdx.x;     // 4*480*128 threads
  int l = t / (KP*HD);
  int rem = t % (KP*HD);
  int r = rem / HD, c = rem % HD;
  const float* Wxl = Wx + l*(HD+HID)*HD;
  float v = 0.f;
  if (r < 128){
    v = Wxl[r*HD + c];
  } else if (r < 464){
    int rm = r - 128;
    const float* wm = Wm + (l*336 + rm)*HID;
    float acc = 0.f;
    for (int h = 0; h < HID; ++h) acc += wm[h] * Wxl[(128+h)*HD + c];
    v = acc;
  } else if (r == 464){
    const float* bml = bm + l*HID;
    float acc = 0.f;
    for (int h = 0; h < HID; ++h) acc += bml[h] * Wxl[(128+h)*HD + c];
    v = acc;
  }
  Wc[t] = v;   // t == (l*KP + r)*HD + c
}

// ---- per-layer edge aggregation: one wave per node ----
__global__ __launch_bounds__(256) void k_edge(const float* __restrict__ xf_cur, const float* __restrict__ posf_cur,
                                              const int* __restrict__ row_ptr, const int* __restrict__ sj,
                                              const int* __restrict__ se, const float* __restrict__ ea,
                                              float* __restrict__ A, float* __restrict__ posf_next){
  int n    = blockIdx.x*4 + (threadIdx.x >> 6);
  int lane = threadIdx.x & 63;
  float2 xiv = *(const float2*)(xf_cur + (long)n*HD + 2*lane);
  float  pi  = (lane < 3) ? posf_cur[n*3 + lane] : 0.f;
  int beg = row_ptr[n], end = row_ptr[n+1];
  float sxj0 = 0.f, sxj1 = 0.f, ssoh = 0.f, sea = 0.f, spos = 0.f;
  float cc = (10.0f/63.0f) * (float)lane;            // linspace(0,10,64)
  for (int e = beg; e < end; ++e){
    int j = sj[e];
    float2 xjv = *(const float2*)(xf_cur + (long)j*HD + 2*lane);
    float d0 = xiv.x - xjv.x, d1 = xiv.y - xjv.y;
    float p = d0*d0 + d1*d1;
    #pragma unroll
    for (int m = 1; m < 64; m <<= 1) p += __shfl_xor(p, m, 64);
    float r = sqrtf(p);
    float tt = r - cc;
    ssoh += __expf(-10.0f * tt * tt);                // GAMMA=10
    sxj0 += xjv.x; sxj1 += xjv.y;
    if (lane < 16) sea  += ea[se[e]*ED + lane];
    if (lane < 3)  spos += posf_cur[j*3 + lane];
  }
  float cf = (float)(end - beg);
  float* Ar = A + (long)n*KP;
  ((float2*)(Ar      ))[lane] = xiv;
  ((float2*)(Ar + 128))[lane] = make_float2(cf*xiv.x, cf*xiv.y);
  ((float2*)(Ar + 256))[lane] = make_float2(sxj0, sxj1);
  Ar[384 + lane] = ssoh;
  if (lane < 16) Ar[448 + lane] = sea;
  if (lane < 16) Ar[464 + lane] = (lane == 0) ? cf : 0.f;
  if (lane < 3)  posf_next[n*3 + lane] = pi + (cf*pi - spos) / fmaxf(cf, 1.f);
}

// ---- node GEMM: C[10000,128] = A[10000,480] @ Wc + bx, leaky, (final: residual+leaky) ----
// BM=32, BN=128, BK=16; 256 threads; micro-tile 4x4
__global__ __launch_bounds__(256) void k_gemm(const float* __restrict__ A, const float* __restrict__ Wc,
                                              const float* __restrict__ bx, float* __restrict__ xf_next,
                                              const float* __restrict__ x_ori, float* __restrict__ out,
                                              int final_flag){
  __shared__ float a_s[16*36];    // [k][r], stride 36 (16B-aligned rows, breaks conflicts)
  __shared__ float w_s[16*128];   // [k][c]
  int t  = threadIdx.x;
  int rb = blockIdx.x * 32;
  int lr = t >> 4, lk = t & 15;        // A loader: 2 elems/thread
  int wcc = t & 127, wk = t >> 7;      // W loader: 8 elems/thread
  int cg = t & 31, rg = t >> 5;        // compute mapping: 8 row-groups x 32 col-groups
  float acc[4][4];
  #pragma unroll
  for (int i = 0; i < 4; ++i)
    #pragma unroll
    for (int j = 0; j < 4; ++j) acc[i][j] = 0.f;
  for (int k0 = 0; k0 < KP; k0 += 16){
    int gr0 = rb + lr, gr1 = rb + lr + 16;
    a_s[lk*36 + lr]      = (gr0 < NN) ? A[(long)gr0*KP + k0 + lk] : 0.f;
    a_s[lk*36 + lr + 16] = (gr1 < NN) ? A[(long)gr1*KP + k0 + lk] : 0.f;
    #pragma unroll
    for (int q = 0; q < 8; ++q)
      w_s[(wk + 2*q)*128 + wcc] = Wc[(k0 + wk + 2*q)*HD + wcc];
    __syncthreads();
    #pragma unroll
    for (int k = 0; k < 16; ++k){
      float4 av = *(const float4*)&a_s[k*36 + rg*4];
      float4 wv = *(const float4*)&w_s[k*128 + cg*4];
      acc[0][0] += av.x*wv.x; acc[0][1] += av.x*wv.y; acc[0][2] += av.x*wv.z; acc[0][3] += av.x*wv.w;
      acc[1][0] += av.y*wv.x; acc[1][1] += av.y*wv.y; acc[1][2] += av.y*wv.z; acc[1][3] += av.y*wv.w;
      acc[2][0] += av.z*wv.x; acc[2][1] += av.z*wv.y; acc[2][2] += av.z*wv.z; acc[2][3] += av.z*wv.w;
      acc[3][0] += av.w*wv.x; acc[3][1] += av.w*wv.y; acc[3][2] += av.w*wv.z; acc[3][3] += av.w*wv.w;
    }
    __syncthreads();
  }
  #pragma unroll
  for (int i = 0; i < 4; ++i){
    int row = rb + rg*4 + i;
    if (row >= NN) break;
    #pragma unroll
    for (int j = 0; j < 4; ++j){
      int col = cg*4 + j;
      float v = acc[i][j] + bx[col];
      v = leaky(v);
      if (final_flag){
        float xo = x_ori[(long)row*HD + col];
        out[(long)row*HD + col] = leaky(xo + v);
      } else {
        xf_next[(long)row*HD + col] = v;
      }
    }
  }
}

extern "C" void kernel_launch(void* const* d_in, const int* in_sizes, int n_in,
                              void* d_out, int out_size, void* d_ws, size_t ws_size,
                              hipStream_t stream){
  const float* x   = (const float*)d_in[0];
  const float* pos = (const float*)d_in[1];
  const int*   ei  = (const int*)d_in[2];
  const float* ea  = (const float*)d_in[3];
  const float* Wm  = (const float*)d_in[4];
  const float* bm  = (const float*)d_in[5];
  // d_in[6] (Wp), d_in[7] (bp): dead code in reference
  const float* Wx  = (const float*)d_in[8];
  const float* bx  = (const float*)d_in[9];
  float* out_x   = (float*)d_out;
  float* out_pos = out_x + NN*HD;

  float* xfA    = (float*)d_ws;
  float* xfB    = xfA + NN*HD;
  float* A      = xfB + NN*HD;
  float* Wc     = A + (long)NN*KP;
  float* pfA    = Wc + 4*KP*HD;
  float* pfB    = pfA + NN*3;
  int*   cnt    = (int*)(pfB + NN*3);
  int*   c2     = cnt + NN;
  int*   row_ptr= c2 + NN;
  int*   sj     = row_ptr + (NN+1);
  int*   se     = sj + NE;
  const int* ii = ei;
  const int* jj = ei + NE;

  hipMemsetAsync(cnt, 0, 2*NN*sizeof(int), stream);                 // cnt + c2
  k_count<<<(NE+255)/256, 256, 0, stream>>>(ii, cnt);
  k_scan <<<1, 256, 0, stream>>>(cnt, row_ptr);
  k_fill <<<(NE+255)/256, 256, 0, stream>>>(ii, jj, row_ptr, c2, sj, se);
  k_wc   <<<(4*KP*HD)/256, 256, 0, stream>>>(Wm, bm, Wx, Wc);

  // buffer ping-pong: layer0 reads inputs directly; layer3 writes pos into d_out
  const float* xs[4] = {x,   xfA, xfB, xfA};
  float*       xd[4] = {xfA, xfB, xfA, out_x};   // xd[3] unused (final path writes out)
  const float* ps[4] = {pos, pfA, pfB, pfA};
  float*       pd[4] = {pfA, pfB, pfA, out_pos};

  for (int l = 0; l < 4; ++l){
    k_edge<<<NN/4, 256, 0, stream>>>(xs[l], ps[l], row_ptr, sj, se, ea, A, pd[l]);
    k_gemm<<<(NN+31)/32, 256, 0, stream>>>(A, Wc + (long)l*KP*HD, bx + l*HD,
                                           xd[l], x, out_x, l == 3 ? 1 : 0);
  }
}

// Round 3
// 606.835 us; speedup vs baseline: 1.3325x; 1.3325x over previous
//
#include <hip/hip_runtime.h>

#define NN 10000      // nodes
#define NE 320000     // edges
#define HD 128        // h_dim
#define ED 16         // e_dim
#define HID 256       // hid_dim
#define NS 64         // n_step
#define KP 480        // padded K: [x 128 | cnt*x 128 | sum_xj 128 | sum_soh 64 | sum_ea 16 | cnt 1 | pad 15]

__device__ __forceinline__ float leaky(float v){ return v > 0.f ? v : 0.01f*v; }

// ---- CSR build ----
__global__ __launch_bounds__(256) void k_count(const int* __restrict__ ii, int* __restrict__ cnt){
  int e = blockIdx.x*256 + threadIdx.x;
  if (e < NE) atomicAdd(&cnt[ii[e]], 1);
}

// one block; each thread owns 40 contiguous nodes; one 256-wide block scan
__global__ __launch_bounds__(256) void k_scan(const int* __restrict__ cnt, int* __restrict__ row_ptr){
  const int PER = 40;                       // 256*40 = 10240 >= NN
  __shared__ int sh[256];
  int t = threadIdx.x;
  int base = t*PER;
  int s = 0;
  for (int k = 0; k < PER; ++k){ int idx = base+k; if (idx < NN) s += cnt[idx]; }
  sh[t] = s; __syncthreads();
  for (int off = 1; off < 256; off <<= 1){
    int v = (t >= off) ? sh[t-off] : 0;
    __syncthreads();
    sh[t] += v;
    __syncthreads();
  }
  int pre = sh[t] - s;                      // exclusive prefix
  for (int k = 0; k < PER; ++k){
    int idx = base+k;
    if (idx < NN){ row_ptr[idx] = pre; pre += cnt[idx]; }
  }
  if (t == 255) row_ptr[NN] = sh[255];
}

__global__ __launch_bounds__(256) void k_fill(const int* __restrict__ ii, const int* __restrict__ jj,
                                              const int* __restrict__ row_ptr, int* __restrict__ c2,
                                              int* __restrict__ si, int* __restrict__ sj, int* __restrict__ se){
  int e = blockIdx.x*256 + threadIdx.x;
  if (e < NE){
    int a = ii[e];
    int p = atomicAdd(&c2[a], 1);
    int idx = row_ptr[a] + p;
    si[idx] = a;
    sj[idx] = jj[e];
    se[idx] = e;
  }
}

// ---- combined weights ----
// top: Wc[l][r][c] = Wx[l][r][c] for r<128
__global__ __launch_bounds__(256) void k_wc_top(const float* __restrict__ Wx, float* __restrict__ Wc){
  int t = blockIdx.x*256 + threadIdx.x;      // 4*128*128
  int l = t >> 14, r = (t >> 7) & 127, c = t & 127;
  Wc[(l*KP + r)*HD + c] = Wx[l*(HD+HID)*HD + r*HD + c];
}

// bot: rows 128..464 of Wc = [Wm_l ; bm_l] @ Wx_l[128:,:]   (M=337, K=256, N=128)
__global__ __launch_bounds__(256) void k_wc_bot(const float* __restrict__ Wm, const float* __restrict__ bm,
                                                const float* __restrict__ Wx, float* __restrict__ Wc){
  __shared__ float a_s[16*36];
  __shared__ float w_s[16*128];
  int t  = threadIdx.x;
  int rb = blockIdx.x * 32;
  int l  = blockIdx.y;
  int lr = t >> 4, lk = t & 15;
  int wcc = t & 127, wk = t >> 7;
  int cg = t & 31, rg = t >> 5;
  const float* Wxb = Wx + l*(HD+HID)*HD + HD*HD;   // bottom 256 rows of Wx_l
  float acc[4][4];
  #pragma unroll
  for (int i = 0; i < 4; ++i)
    #pragma unroll
    for (int j = 0; j < 4; ++j) acc[i][j] = 0.f;
  for (int k0 = 0; k0 < HID; k0 += 16){
    int m0 = rb + lr, m1 = rb + lr + 16;
    float v0 = 0.f, v1 = 0.f;
    if (m0 < 336) v0 = Wm[(l*336 + m0)*HID + k0 + lk];
    else if (m0 == 336) v0 = bm[l*HID + k0 + lk];
    if (m1 < 336) v1 = Wm[(l*336 + m1)*HID + k0 + lk];
    else if (m1 == 336) v1 = bm[l*HID + k0 + lk];
    a_s[lk*36 + lr]      = v0;
    a_s[lk*36 + lr + 16] = v1;
    #pragma unroll
    for (int q = 0; q < 8; ++q)
      w_s[(wk + 2*q)*128 + wcc] = Wxb[(k0 + wk + 2*q)*HD + wcc];
    __syncthreads();
    #pragma unroll
    for (int k = 0; k < 16; ++k){
      float4 av = *(const float4*)&a_s[k*36 + rg*4];
      float4 wv = *(const float4*)&w_s[k*128 + cg*4];
      acc[0][0] += av.x*wv.x; acc[0][1] += av.x*wv.y; acc[0][2] += av.x*wv.z; acc[0][3] += av.x*wv.w;
      acc[1][0] += av.y*wv.x; acc[1][1] += av.y*wv.y; acc[1][2] += av.y*wv.z; acc[1][3] += av.y*wv.w;
      acc[2][0] += av.z*wv.x; acc[2][1] += av.z*wv.y; acc[2][2] += av.z*wv.z; acc[2][3] += av.z*wv.w;
      acc[3][0] += av.w*wv.x; acc[3][1] += av.w*wv.y; acc[3][2] += av.w*wv.z; acc[3][3] += av.w*wv.w;
    }
    __syncthreads();
  }
  #pragma unroll
  for (int i = 0; i < 4; ++i){
    int m = rb + rg*4 + i;
    if (m < 337){
      #pragma unroll
      for (int j = 0; j < 4; ++j)
        Wc[(l*KP + 128 + m)*HD + cg*4 + j] = acc[i][j];
    }
  }
}

// ---- once per call: layer-invariant A segments (sum_ea, cnt, pad) ----
__global__ __launch_bounds__(256) void k_prep(const int* __restrict__ row_ptr, const int* __restrict__ se,
                                              const float* __restrict__ ea, float* __restrict__ A){
  int n    = blockIdx.x*4 + (threadIdx.x >> 6);
  int lane = threadIdx.x & 63;
  int beg = row_ptr[n], end = row_ptr[n+1];
  int q = lane >> 4, c = lane & 15;
  float acc = 0.f;
  for (int it = beg + q; it < end; it += 4)
    acc += ea[se[it]*ED + c];
  acc += __shfl_xor(acc, 16, 64);
  acc += __shfl_xor(acc, 32, 64);
  float* Ar = A + (long)n*KP;
  if (lane < 16) Ar[448 + lane] = acc;
  if (lane == 0) Ar[464] = (float)(end - beg);
  if (lane >= 1 && lane < 16) Ar[464 + lane] = 0.f;
}

// ---- per-layer pass 1: edge-parallel distances (CSR order), 32 lanes per edge ----
__global__ __launch_bounds__(256) void k_dist(const float* __restrict__ xf,
                                              const int* __restrict__ si, const int* __restrict__ sj,
                                              float* __restrict__ rq){
  int w = (blockIdx.x*256 + threadIdx.x) >> 5;   // CSR index
  int h = threadIdx.x & 31;
  if (w >= NE) return;
  int i = si[w], j = sj[w];
  float4 a = *(const float4*)(xf + (long)i*HD + 4*h);
  float4 b = *(const float4*)(xf + (long)j*HD + 4*h);
  float dx = a.x-b.x, dy = a.y-b.y, dz = a.z-b.z, dw = a.w-b.w;
  float p = dx*dx + dy*dy + dz*dz + dw*dw;
  #pragma unroll
  for (int m = 1; m < 32; m <<= 1) p += __shfl_xor(p, m, 64);
  if (h == 0) rq[w] = sqrtf(p);
}

// ---- per-layer pass 2: wave-per-node aggregation (no cross-lane ops in loop) ----
__global__ __launch_bounds__(256) void k_aggr(const float* __restrict__ xf_cur, const float* __restrict__ posf_cur,
                                              const int* __restrict__ row_ptr, const int* __restrict__ sj,
                                              const float* __restrict__ rq,
                                              float* __restrict__ A, float* __restrict__ posf_next){
  int n    = blockIdx.x*4 + (threadIdx.x >> 6);
  int lane = threadIdx.x & 63;
  float2 xiv = *(const float2*)(xf_cur + (long)n*HD + 2*lane);
  float  pi  = (lane < 3) ? posf_cur[n*3 + lane] : 0.f;
  int beg = row_ptr[n], end = row_ptr[n+1];
  float sxj0 = 0.f, sxj1 = 0.f, ssoh = 0.f, spos = 0.f;
  float cc = (10.0f/63.0f) * (float)lane;
  int idx = beg;
  for (; idx + 1 < end; idx += 2){
    int j0 = sj[idx], j1 = sj[idx+1];
    float r0 = rq[idx], r1 = rq[idx+1];
    float2 a0 = *(const float2*)(xf_cur + (long)j0*HD + 2*lane);
    float2 a1 = *(const float2*)(xf_cur + (long)j1*HD + 2*lane);
    sxj0 += a0.x + a1.x;
    sxj1 += a0.y + a1.y;
    float t0 = r0 - cc, t1 = r1 - cc;
    ssoh += __expf(-10.0f*t0*t0) + __expf(-10.0f*t1*t1);
    if (lane < 3) spos += posf_cur[j0*3 + lane] + posf_cur[j1*3 + lane];
  }
  if (idx < end){
    int j0 = sj[idx];
    float r0 = rq[idx];
    float2 a0 = *(const float2*)(xf_cur + (long)j0*HD + 2*lane);
    sxj0 += a0.x; sxj1 += a0.y;
    float t0 = r0 - cc;
    ssoh += __expf(-10.0f*t0*t0);
    if (lane < 3) spos += posf_cur[j0*3 + lane];
  }
  float cf = (float)(end - beg);
  float* Ar = A + (long)n*KP;
  ((float2*)(Ar      ))[lane] = xiv;
  ((float2*)(Ar + 128))[lane] = make_float2(cf*xiv.x, cf*xiv.y);
  ((float2*)(Ar + 256))[lane] = make_float2(sxj0, sxj1);
  Ar[384 + lane] = ssoh;
  if (lane < 3) posf_next[n*3 + lane] = pi + (cf*pi - spos) / fmaxf(cf, 1.f);
}

// ---- node GEMM: C[10000,128] = A[10000,480] @ Wc + bx, leaky, (final: residual+leaky) ----
__global__ __launch_bounds__(256) void k_gemm(const float* __restrict__ A, const float* __restrict__ Wc,
                                              const float* __restrict__ bx, float* __restrict__ xf_next,
                                              const float* __restrict__ x_ori, float* __restrict__ out,
                                              int final_flag){
  __shared__ float a_s[16*36];
  __shared__ float w_s[16*128];
  int t  = threadIdx.x;
  int rb = blockIdx.x * 32;
  int lr = t >> 4, lk = t & 15;
  int wcc = t & 127, wk = t >> 7;
  int cg = t & 31, rg = t >> 5;
  float acc[4][4];
  #pragma unroll
  for (int i = 0; i < 4; ++i)
    #pragma unroll
    for (int j = 0; j < 4; ++j) acc[i][j] = 0.f;
  for (int k0 = 0; k0 < KP; k0 += 16){
    int gr0 = rb + lr, gr1 = rb + lr + 16;
    a_s[lk*36 + lr]      = (gr0 < NN) ? A[(long)gr0*KP + k0 + lk] : 0.f;
    a_s[lk*36 + lr + 16] = (gr1 < NN) ? A[(long)gr1*KP + k0 + lk] : 0.f;
    #pragma unroll
    for (int q = 0; q < 8; ++q)
      w_s[(wk + 2*q)*128 + wcc] = Wc[(k0 + wk + 2*q)*HD + wcc];
    __syncthreads();
    #pragma unroll
    for (int k = 0; k < 16; ++k){
      float4 av = *(const float4*)&a_s[k*36 + rg*4];
      float4 wv = *(const float4*)&w_s[k*128 + cg*4];
      acc[0][0] += av.x*wv.x; acc[0][1] += av.x*wv.y; acc[0][2] += av.x*wv.z; acc[0][3] += av.x*wv.w;
      acc[1][0] += av.y*wv.x; acc[1][1] += av.y*wv.y; acc[1][2] += av.y*wv.z; acc[1][3] += av.y*wv.w;
      acc[2][0] += av.z*wv.x; acc[2][1] += av.z*wv.y; acc[2][2] += av.z*wv.z; acc[2][3] += av.z*wv.w;
      acc[3][0] += av.w*wv.x; acc[3][1] += av.w*wv.y; acc[3][2] += av.w*wv.z; acc[3][3] += av.w*wv.w;
    }
    __syncthreads();
  }
  #pragma unroll
  for (int i = 0; i < 4; ++i){
    int row = rb + rg*4 + i;
    if (row >= NN) break;
    #pragma unroll
    for (int j = 0; j < 4; ++j){
      int col = cg*4 + j;
      float v = acc[i][j] + bx[col];
      v = leaky(v);
      if (final_flag){
        float xo = x_ori[(long)row*HD + col];
        out[(long)row*HD + col] = leaky(xo + v);
      } else {
        xf_next[(long)row*HD + col] = v;
      }
    }
  }
}

extern "C" void kernel_launch(void* const* d_in, const int* in_sizes, int n_in,
                              void* d_out, int out_size, void* d_ws, size_t ws_size,
                              hipStream_t stream){
  const float* x   = (const float*)d_in[0];
  const float* pos = (const float*)d_in[1];
  const int*   ei  = (const int*)d_in[2];
  const float* ea  = (const float*)d_in[3];
  const float* Wm  = (const float*)d_in[4];
  const float* bm  = (const float*)d_in[5];
  const float* Wx  = (const float*)d_in[8];
  const float* bx  = (const float*)d_in[9];
  float* out_x   = (float*)d_out;
  float* out_pos = out_x + NN*HD;

  float* xfA    = (float*)d_ws;
  float* xfB    = xfA + NN*HD;
  float* A      = xfB + NN*HD;
  float* Wc     = A + (long)NN*KP;
  float* pfA    = Wc + 4*KP*HD;
  float* pfB    = pfA + NN*3;
  float* rq     = pfB + NN*3;
  int*   cnt    = (int*)(rq + NE);
  int*   c2     = cnt + NN;
  int*   row_ptr= c2 + NN;
  int*   si     = row_ptr + (NN+1);
  int*   sj     = si + NE;
  int*   se     = sj + NE;
  const int* ii = ei;
  const int* jj = ei + NE;

  hipMemsetAsync(cnt, 0, 2*NN*sizeof(int), stream);
  k_count <<<(NE+255)/256, 256, 0, stream>>>(ii, cnt);
  k_scan  <<<1, 256, 0, stream>>>(cnt, row_ptr);
  k_fill  <<<(NE+255)/256, 256, 0, stream>>>(ii, jj, row_ptr, c2, si, sj, se);
  k_wc_top<<<(4*HD*HD)/256, 256, 0, stream>>>(Wx, Wc);
  k_wc_bot<<<dim3(11, 4), 256, 0, stream>>>(Wm, bm, Wx, Wc);
  k_prep  <<<NN/4, 256, 0, stream>>>(row_ptr, se, ea, A);

  const float* xs[4] = {x,   xfA, xfB, xfA};
  float*       xd[4] = {xfA, xfB, xfA, out_x};
  const float* ps[4] = {pos, pfA, pfB, pfA};
  float*       pd[4] = {pfA, pfB, pfA, out_pos};

  for (int l = 0; l < 4; ++l){
    k_dist<<<(NE*32 + 255)/256, 256, 0, stream>>>(xs[l], si, sj, rq);
    k_aggr<<<NN/4, 256, 0, stream>>>(xs[l], ps[l], row_ptr, sj, rq, A, pd[l]);
    k_gemm<<<(NN+31)/32, 256, 0, stream>>>(A, Wc + (long)l*KP*HD, bx + l*HD,
                                           xd[l], x, out_x, l == 3 ? 1 : 0);
  }
}

// Round 4
// 430.883 us; speedup vs baseline: 1.8767x; 1.4084x over previous
//
#include <hip/hip_runtime.h>
#include <hip/hip_bf16.h>

#define NN 10000      // nodes
#define NE 320000     // edges
#define HD 128        // h_dim
#define ED 16         // e_dim
#define HID 256       // hid_dim
#define KP 480        // A row: [x 128 | cnt*x 128 | sum_xj 128 | sum_soh 64 | sum_ea 16 | cnt 1 | pad 15]
#define AROWS 10048   // NN padded to block multiple

typedef unsigned short ushort_t;
typedef __attribute__((ext_vector_type(8))) short short8;
typedef __attribute__((ext_vector_type(4))) float f32x4;

__device__ __forceinline__ float leaky(float v){ return v > 0.f ? v : 0.01f*v; }
__device__ __forceinline__ ushort_t f2bs(float v){
  __hip_bfloat16 b = __float2bfloat16(v);
  return *(ushort_t*)&b;
}
__device__ __forceinline__ ushort2 pack2(float a, float b){
  ushort2 r; r.x = f2bs(a); r.y = f2bs(b); return r;
}

// ---- CSR build ----
__global__ __launch_bounds__(256) void k_count(const int* __restrict__ ii, int* __restrict__ cnt){
  int e = blockIdx.x*256 + threadIdx.x;
  if (e < NE) atomicAdd(&cnt[ii[e]], 1);
}

__global__ __launch_bounds__(256) void k_scan(const int* __restrict__ cnt, int* __restrict__ row_ptr){
  const int PER = 40;
  __shared__ int sh[256];
  int t = threadIdx.x;
  int base = t*PER;
  int s = 0;
  for (int k = 0; k < PER; ++k){ int idx = base+k; if (idx < NN) s += cnt[idx]; }
  sh[t] = s; __syncthreads();
  for (int off = 1; off < 256; off <<= 1){
    int v = (t >= off) ? sh[t-off] : 0;
    __syncthreads();
    sh[t] += v;
    __syncthreads();
  }
  int pre = sh[t] - s;
  for (int k = 0; k < PER; ++k){
    int idx = base+k;
    if (idx < NN){ row_ptr[idx] = pre; pre += cnt[idx]; }
  }
  if (t == 255) row_ptr[NN] = sh[255];
}

__global__ __launch_bounds__(256) void k_fill(const int* __restrict__ ii, const int* __restrict__ jj,
                                              const int* __restrict__ row_ptr, int* __restrict__ c2,
                                              int* __restrict__ si, int* __restrict__ sj, int* __restrict__ se){
  int e = blockIdx.x*256 + threadIdx.x;
  if (e < NE){
    int a = ii[e];
    int p = atomicAdd(&c2[a], 1);
    int idx = row_ptr[a] + p;
    si[idx] = a;
    sj[idx] = jj[e];
    se[idx] = e;
  }
}

// ---- combined weights, stored TRANSPOSED bf16: WcT[l][n(128)][k(480)] ----
// k<128: Wx_top^T ; 128..464: ([Wm;bm] @ Wx_bot)^T ; 465..479: zero (memset)
__global__ __launch_bounds__(256) void k_wc_top(const float* __restrict__ Wx, ushort_t* __restrict__ WcT){
  int t = blockIdx.x*256 + threadIdx.x;      // 4*128*128
  int l = t >> 14, r = (t >> 7) & 127, c = t & 127;
  WcT[((long)l*HD + c)*KP + r] = f2bs(Wx[(long)l*(HD+HID)*HD + r*HD + c]);
}

__global__ __launch_bounds__(256) void k_wc_bot(const float* __restrict__ Wm, const float* __restrict__ bm,
                                                const float* __restrict__ Wx, ushort_t* __restrict__ WcT){
  __shared__ float a_s[16*36];
  __shared__ float w_s[16*128];
  int t  = threadIdx.x;
  int rb = blockIdx.x * 32;
  int l  = blockIdx.y;
  int lr = t >> 4, lk = t & 15;
  int wcc = t & 127, wk = t >> 7;
  int cg = t & 31, rg = t >> 5;
  const float* Wxb = Wx + (long)l*(HD+HID)*HD + HD*HD;
  float acc[4][4];
  #pragma unroll
  for (int i = 0; i < 4; ++i)
    #pragma unroll
    for (int j = 0; j < 4; ++j) acc[i][j] = 0.f;
  for (int k0 = 0; k0 < HID; k0 += 16){
    int m0 = rb + lr, m1 = rb + lr + 16;
    float v0 = 0.f, v1 = 0.f;
    if (m0 < 336) v0 = Wm[((long)l*336 + m0)*HID + k0 + lk];
    else if (m0 == 336) v0 = bm[l*HID + k0 + lk];
    if (m1 < 336) v1 = Wm[((long)l*336 + m1)*HID + k0 + lk];
    else if (m1 == 336) v1 = bm[l*HID + k0 + lk];
    a_s[lk*36 + lr]      = v0;
    a_s[lk*36 + lr + 16] = v1;
    #pragma unroll
    for (int q = 0; q < 8; ++q)
      w_s[(wk + 2*q)*128 + wcc] = Wxb[(k0 + wk + 2*q)*HD + wcc];
    __syncthreads();
    #pragma unroll
    for (int k = 0; k < 16; ++k){
      float4 av = *(const float4*)&a_s[k*36 + rg*4];
      float4 wv = *(const float4*)&w_s[k*128 + cg*4];
      acc[0][0] += av.x*wv.x; acc[0][1] += av.x*wv.y; acc[0][2] += av.x*wv.z; acc[0][3] += av.x*wv.w;
      acc[1][0] += av.y*wv.x; acc[1][1] += av.y*wv.y; acc[1][2] += av.y*wv.z; acc[1][3] += av.y*wv.w;
      acc[2][0] += av.z*wv.x; acc[2][1] += av.z*wv.y; acc[2][2] += av.z*wv.z; acc[2][3] += av.z*wv.w;
      acc[3][0] += av.w*wv.x; acc[3][1] += av.w*wv.y; acc[3][2] += av.w*wv.z; acc[3][3] += av.w*wv.w;
    }
    __syncthreads();
  }
  #pragma unroll
  for (int i = 0; i < 4; ++i){
    int m = rb + rg*4 + i;
    if (m < 337){
      #pragma unroll
      for (int j = 0; j < 4; ++j)
        WcT[((long)l*HD + cg*4 + j)*KP + 128 + m] = f2bs(acc[i][j]);
    }
  }
}

// ---- once per call: layer-invariant A segments (sum_ea, cnt, pad) in bf16 ----
__global__ __launch_bounds__(256) void k_prep(const int* __restrict__ row_ptr, const int* __restrict__ se,
                                              const float* __restrict__ ea, ushort_t* __restrict__ Ab){
  int n    = blockIdx.x*4 + (threadIdx.x >> 6);
  int lane = threadIdx.x & 63;
  int beg = row_ptr[n], end = row_ptr[n+1];
  int q = lane >> 4, c = lane & 15;
  float acc = 0.f;
  for (int it = beg + q; it < end; it += 4)
    acc += ea[se[it]*ED + c];
  acc += __shfl_xor(acc, 16, 64);
  acc += __shfl_xor(acc, 32, 64);
  ushort_t* Ar = Ab + (long)n*KP;
  if (lane < 16) Ar[448 + lane] = f2bs(acc);
  if (lane < 16) Ar[464 + lane] = (lane == 0) ? f2bs((float)(end - beg)) : (ushort_t)0;
}

// ---- per-layer pass 1: edge-parallel distances, 16 lanes per edge ----
__global__ __launch_bounds__(256) void k_dist(const float* __restrict__ xf,
                                              const int* __restrict__ si, const int* __restrict__ sj,
                                              float* __restrict__ rq){
  int g = blockIdx.x*256 + threadIdx.x;
  int w = g >> 4;
  int h = g & 15;
  if (w >= NE) return;
  int i = si[w], j = sj[w];
  const float4* xi = (const float4*)(xf + (long)i*HD);
  const float4* xj = (const float4*)(xf + (long)j*HD);
  float4 a0 = xi[2*h], b0 = xj[2*h];
  float4 a1 = xi[2*h+1], b1 = xj[2*h+1];
  float d0 = a0.x-b0.x, d1 = a0.y-b0.y, d2 = a0.z-b0.z, d3 = a0.w-b0.w;
  float d4 = a1.x-b1.x, d5 = a1.y-b1.y, d6 = a1.z-b1.z, d7 = a1.w-b1.w;
  float p = d0*d0 + d1*d1 + d2*d2 + d3*d3 + d4*d4 + d5*d5 + d6*d6 + d7*d7;
  #pragma unroll
  for (int m = 1; m < 16; m <<= 1) p += __shfl_xor(p, m, 64);
  if (h == 0) rq[w] = sqrtf(p);
}

// ---- per-layer pass 2: wave-per-node aggregation, writes bf16 A row ----
__global__ __launch_bounds__(256) void k_aggr(const float* __restrict__ xf_cur, const float* __restrict__ posf_cur,
                                              const int* __restrict__ row_ptr, const int* __restrict__ sj,
                                              const float* __restrict__ rq,
                                              ushort_t* __restrict__ Ab, float* __restrict__ posf_next){
  int n    = blockIdx.x*4 + (threadIdx.x >> 6);
  int lane = threadIdx.x & 63;
  float2 xiv = *(const float2*)(xf_cur + (long)n*HD + 2*lane);
  float  pi  = (lane < 3) ? posf_cur[n*3 + lane] : 0.f;
  int beg = row_ptr[n], end = row_ptr[n+1];
  float sxj0 = 0.f, sxj1 = 0.f, ssoh = 0.f, spos = 0.f;
  float cc = (10.0f/63.0f) * (float)lane;
  int idx = beg;
  for (; idx + 3 < end; idx += 4){
    int j0 = sj[idx], j1 = sj[idx+1], j2 = sj[idx+2], j3 = sj[idx+3];
    float r0 = rq[idx], r1 = rq[idx+1], r2 = rq[idx+2], r3 = rq[idx+3];
    float2 a0 = *(const float2*)(xf_cur + (long)j0*HD + 2*lane);
    float2 a1 = *(const float2*)(xf_cur + (long)j1*HD + 2*lane);
    float2 a2 = *(const float2*)(xf_cur + (long)j2*HD + 2*lane);
    float2 a3 = *(const float2*)(xf_cur + (long)j3*HD + 2*lane);
    sxj0 += (a0.x + a1.x) + (a2.x + a3.x);
    sxj1 += (a0.y + a1.y) + (a2.y + a3.y);
    float t0 = r0 - cc, t1 = r1 - cc, t2 = r2 - cc, t3 = r3 - cc;
    ssoh += __expf(-10.0f*t0*t0) + __expf(-10.0f*t1*t1)
          + __expf(-10.0f*t2*t2) + __expf(-10.0f*t3*t3);
    if (lane < 3) spos += (posf_cur[j0*3 + lane] + posf_cur[j1*3 + lane])
                        + (posf_cur[j2*3 + lane] + posf_cur[j3*3 + lane]);
  }
  for (; idx < end; ++idx){
    int j0 = sj[idx];
    float r0 = rq[idx];
    float2 a0 = *(const float2*)(xf_cur + (long)j0*HD + 2*lane);
    sxj0 += a0.x; sxj1 += a0.y;
    float t0 = r0 - cc;
    ssoh += __expf(-10.0f*t0*t0);
    if (lane < 3) spos += posf_cur[j0*3 + lane];
  }
  float cf = (float)(end - beg);
  ushort_t* Ar = Ab + (long)n*KP;
  ((ushort2*)Ar)[lane]       = pack2(xiv.x, xiv.y);
  ((ushort2*)Ar)[64 + lane]  = pack2(cf*xiv.x, cf*xiv.y);
  ((ushort2*)Ar)[128 + lane] = pack2(sxj0, sxj1);
  Ar[384 + lane] = f2bs(ssoh);
  if (lane < 3) posf_next[n*3 + lane] = pi + (cf*pi - spos) / fmaxf(cf, 1.f);
}

// ---- node GEMM via MFMA, no LDS: C[NN,128] = A[NN,480]bf16 @ WcT^T + bx ----
// 313 blocks x 256 thr; wave handles 16 rows x 64 cols (4 tiles of 16x16x(K=480))
__global__ __launch_bounds__(256) void k_gemm(const ushort_t* __restrict__ A, const ushort_t* __restrict__ WcT,
                                              const float* __restrict__ bx, float* __restrict__ xf_next,
                                              const float* __restrict__ x_ori, float* __restrict__ out,
                                              int final_flag){
  int wave = threadIdx.x >> 6, lane = threadIdx.x & 63;
  int quad = lane >> 4, l16 = lane & 15;
  int mbase = blockIdx.x*32 + (wave & 1)*16;
  int nbase = (wave >> 1)*64;
  const ushort_t* Arow = A + (long)(mbase + l16)*KP + quad*8;
  const ushort_t* Wbase = WcT + (long)nbase*KP + quad*8;
  f32x4 acc[4] = {f32x4{0,0,0,0}, f32x4{0,0,0,0}, f32x4{0,0,0,0}, f32x4{0,0,0,0}};
  for (int k0 = 0; k0 < KP; k0 += 32){
    short8 av = *(const short8*)(Arow + k0);
    #pragma unroll
    for (int t = 0; t < 4; ++t){
      short8 bv = *(const short8*)(Wbase + (long)(t*16 + l16)*KP + k0);
      acc[t] = __builtin_amdgcn_mfma_f32_16x16x32_bf16(av, bv, acc[t], 0, 0, 0);
    }
  }
  #pragma unroll
  for (int t = 0; t < 4; ++t){
    int col = nbase + t*16 + l16;
    float bxc = bx[col];
    #pragma unroll
    for (int r = 0; r < 4; ++r){
      int row = mbase + quad*4 + r;
      if (row < NN){
        float v = leaky(acc[t][r] + bxc);
        if (final_flag){
          out[(long)row*HD + col] = leaky(x_ori[(long)row*HD + col] + v);
        } else {
          xf_next[(long)row*HD + col] = v;
        }
      }
    }
  }
}

extern "C" void kernel_launch(void* const* d_in, const int* in_sizes, int n_in,
                              void* d_out, int out_size, void* d_ws, size_t ws_size,
                              hipStream_t stream){
  const float* x   = (const float*)d_in[0];
  const float* pos = (const float*)d_in[1];
  const int*   ei  = (const int*)d_in[2];
  const float* ea  = (const float*)d_in[3];
  const float* Wm  = (const float*)d_in[4];
  const float* bm  = (const float*)d_in[5];
  const float* Wx  = (const float*)d_in[8];
  const float* bx  = (const float*)d_in[9];
  float* out_x   = (float*)d_out;
  float* out_pos = out_x + NN*HD;

  float*    xfA    = (float*)d_ws;
  float*    xfB    = xfA + NN*HD;
  float*    pfA    = xfB + NN*HD;
  float*    pfB    = pfA + NN*3;
  float*    rq     = pfB + NN*3;
  ushort_t* Ab     = (ushort_t*)(rq + NE);
  ushort_t* WcT    = Ab + (long)AROWS*KP;
  int*      cnt    = (int*)(WcT + 4*HD*KP);
  int*      c2     = cnt + NN;
  int*      row_ptr= c2 + NN;
  int*      si     = row_ptr + (NN+1);
  int*      sj     = si + NE;
  int*      se     = sj + NE;
  const int* ii = ei;
  const int* jj = ei + NE;

  hipMemsetAsync(cnt, 0, 2*NN*sizeof(int), stream);
  hipMemsetAsync(WcT, 0, (size_t)4*HD*KP*sizeof(ushort_t), stream);   // zeroes K-pad 465..479
  k_count <<<(NE+255)/256, 256, 0, stream>>>(ii, cnt);
  k_scan  <<<1, 256, 0, stream>>>(cnt, row_ptr);
  k_fill  <<<(NE+255)/256, 256, 0, stream>>>(ii, jj, row_ptr, c2, si, sj, se);
  k_wc_top<<<(4*HD*HD)/256, 256, 0, stream>>>(Wx, WcT);
  k_wc_bot<<<dim3(11, 4), 256, 0, stream>>>(Wm, bm, Wx, WcT);
  k_prep  <<<NN/4, 256, 0, stream>>>(row_ptr, se, ea, Ab);

  const float* xs[4] = {x,   xfA, xfB, xfA};
  float*       xd[4] = {xfA, xfB, xfA, out_x};
  const float* ps[4] = {pos, pfA, pfB, pfA};
  float*       pd[4] = {pfA, pfB, pfA, out_pos};

  for (int l = 0; l < 4; ++l){
    k_dist<<<(NE*16 + 255)/256, 256, 0, stream>>>(xs[l], si, sj, rq);
    k_aggr<<<NN/4, 256, 0, stream>>>(xs[l], ps[l], row_ptr, sj, rq, Ab, pd[l]);
    k_gemm<<<(NN+31)/32, 256, 0, stream>>>(Ab, WcT + (long)l*HD*KP, bx + l*HD,
                                           xd[l], x, out_x, l == 3 ? 1 : 0);
  }
}

// Round 5
// 396.623 us; speedup vs baseline: 2.0388x; 1.0864x over previous
//
#include <hip/hip_runtime.h>
#include <hip/hip_bf16.h>

#define NN 10000      // nodes
#define NE 320000     // edges
#define HD 128        // h_dim
#define ED 16         // e_dim
#define HID 256       // hid_dim
#define KP 480        // A row: [x 128 | cnt*x 128 | sum_xj 128 | sum_soh 64 | sum_ea 16 | cnt 1 | pad 15]
#define AROWS 10048

typedef unsigned short ushort_t;
typedef __attribute__((ext_vector_type(8))) short short8;
typedef __attribute__((ext_vector_type(4))) float f32x4;

__device__ __forceinline__ float leaky(float v){ return v > 0.f ? v : 0.01f*v; }
__device__ __forceinline__ ushort_t f2bs(float v){
  __hip_bfloat16 b = __float2bfloat16(v);
  return *(ushort_t*)&b;
}
__device__ __forceinline__ ushort2 pack2(float a, float b){
  ushort2 r; r.x = f2bs(a); r.y = f2bs(b); return r;
}
__device__ __forceinline__ float bl(unsigned u){ return __uint_as_float(u << 16); }
__device__ __forceinline__ float bh(unsigned u){ return __uint_as_float(u & 0xffff0000u); }

// ---- seed: fp32 input x -> bf16 table ----
__global__ __launch_bounds__(256) void k_seed(const float* __restrict__ x, ushort_t* __restrict__ xb){
  int t = blockIdx.x*256 + threadIdx.x;
  if (t < NN*HD) xb[t] = f2bs(x[t]);
}

// ---- CSR build ----
__global__ __launch_bounds__(256) void k_count(const int* __restrict__ ii, int* __restrict__ cnt){
  int e = blockIdx.x*256 + threadIdx.x;
  if (e < NE) atomicAdd(&cnt[ii[e]], 1);
}

__global__ __launch_bounds__(256) void k_scan(const int* __restrict__ cnt, int* __restrict__ row_ptr){
  const int PER = 40;
  __shared__ int sh[256];
  int t = threadIdx.x;
  int base = t*PER;
  int s = 0;
  for (int k = 0; k < PER; ++k){ int idx = base+k; if (idx < NN) s += cnt[idx]; }
  sh[t] = s; __syncthreads();
  for (int off = 1; off < 256; off <<= 1){
    int v = (t >= off) ? sh[t-off] : 0;
    __syncthreads();
    sh[t] += v;
    __syncthreads();
  }
  int pre = sh[t] - s;
  for (int k = 0; k < PER; ++k){
    int idx = base+k;
    if (idx < NN){ row_ptr[idx] = pre; pre += cnt[idx]; }
  }
  if (t == 255) row_ptr[NN] = sh[255];
}

__global__ __launch_bounds__(256) void k_fill(const int* __restrict__ ii, const int* __restrict__ jj,
                                              const int* __restrict__ row_ptr, int* __restrict__ c2,
                                              int* __restrict__ si, int* __restrict__ sj, int* __restrict__ se){
  int e = blockIdx.x*256 + threadIdx.x;
  if (e < NE){
    int a = ii[e];
    int p = atomicAdd(&c2[a], 1);
    int idx = row_ptr[a] + p;
    si[idx] = a;
    sj[idx] = jj[e];
    se[idx] = e;
  }
}

// ---- combined weights, TRANSPOSED bf16: WcT[l][n(128)][k(480)] ----
__global__ __launch_bounds__(256) void k_wc_top(const float* __restrict__ Wx, ushort_t* __restrict__ WcT){
  int t = blockIdx.x*256 + threadIdx.x;
  int l = t >> 14, r = (t >> 7) & 127, c = t & 127;
  WcT[((long)l*HD + c)*KP + r] = f2bs(Wx[(long)l*(HD+HID)*HD + r*HD + c]);
}

__global__ __launch_bounds__(256) void k_wc_bot(const float* __restrict__ Wm, const float* __restrict__ bm,
                                                const float* __restrict__ Wx, ushort_t* __restrict__ WcT){
  __shared__ float a_s[16*36];
  __shared__ float w_s[16*128];
  int t  = threadIdx.x;
  int rb = blockIdx.x * 32;
  int l  = blockIdx.y;
  int lr = t >> 4, lk = t & 15;
  int wcc = t & 127, wk = t >> 7;
  int cg = t & 31, rg = t >> 5;
  const float* Wxb = Wx + (long)l*(HD+HID)*HD + HD*HD;
  float acc[4][4];
  #pragma unroll
  for (int i = 0; i < 4; ++i)
    #pragma unroll
    for (int j = 0; j < 4; ++j) acc[i][j] = 0.f;
  for (int k0 = 0; k0 < HID; k0 += 16){
    int m0 = rb + lr, m1 = rb + lr + 16;
    float v0 = 0.f, v1 = 0.f;
    if (m0 < 336) v0 = Wm[((long)l*336 + m0)*HID + k0 + lk];
    else if (m0 == 336) v0 = bm[l*HID + k0 + lk];
    if (m1 < 336) v1 = Wm[((long)l*336 + m1)*HID + k0 + lk];
    else if (m1 == 336) v1 = bm[l*HID + k0 + lk];
    a_s[lk*36 + lr]      = v0;
    a_s[lk*36 + lr + 16] = v1;
    #pragma unroll
    for (int q = 0; q < 8; ++q)
      w_s[(wk + 2*q)*128 + wcc] = Wxb[(k0 + wk + 2*q)*HD + wcc];
    __syncthreads();
    #pragma unroll
    for (int k = 0; k < 16; ++k){
      float4 av = *(const float4*)&a_s[k*36 + rg*4];
      float4 wv = *(const float4*)&w_s[k*128 + cg*4];
      acc[0][0] += av.x*wv.x; acc[0][1] += av.x*wv.y; acc[0][2] += av.x*wv.z; acc[0][3] += av.x*wv.w;
      acc[1][0] += av.y*wv.x; acc[1][1] += av.y*wv.y; acc[1][2] += av.y*wv.z; acc[1][3] += av.y*wv.w;
      acc[2][0] += av.z*wv.x; acc[2][1] += av.z*wv.y; acc[2][2] += av.z*wv.z; acc[2][3] += av.z*wv.w;
      acc[3][0] += av.w*wv.x; acc[3][1] += av.w*wv.y; acc[3][2] += av.w*wv.z; acc[3][3] += av.w*wv.w;
    }
    __syncthreads();
  }
  #pragma unroll
  for (int i = 0; i < 4; ++i){
    int m = rb + rg*4 + i;
    if (m < 337){
      #pragma unroll
      for (int j = 0; j < 4; ++j)
        WcT[((long)l*HD + cg*4 + j)*KP + 128 + m] = f2bs(acc[i][j]);
    }
  }
}

// ---- once per call: layer-invariant A segments (sum_ea, cnt, pad) ----
__global__ __launch_bounds__(256) void k_prep(const int* __restrict__ row_ptr, const int* __restrict__ se,
                                              const float* __restrict__ ea, ushort_t* __restrict__ Ab){
  int n    = blockIdx.x*4 + (threadIdx.x >> 6);
  int lane = threadIdx.x & 63;
  int beg = row_ptr[n], end = row_ptr[n+1];
  int q = lane >> 4, c = lane & 15;
  float acc = 0.f;
  for (int it = beg + q; it < end; it += 4)
    acc += ea[se[it]*ED + c];
  acc += __shfl_xor(acc, 16, 64);
  acc += __shfl_xor(acc, 32, 64);
  ushort_t* Ar = Ab + (long)n*KP;
  if (lane < 16) Ar[448 + lane] = f2bs(acc);
  if (lane < 16) Ar[464 + lane] = (lane == 0) ? f2bs((float)(end - beg)) : (ushort_t)0;
}

// ---- pass 1: edge-parallel distances over bf16 x, 16 lanes/edge ----
__global__ __launch_bounds__(256) void k_dist(const unsigned* __restrict__ xbu,
                                              const int* __restrict__ si, const int* __restrict__ sj,
                                              float* __restrict__ rq){
  int g = blockIdx.x*256 + threadIdx.x;
  int w = g >> 4;
  int h = g & 15;
  if (w >= NE) return;
  int i = si[w], j = sj[w];
  uint4 a = ((const uint4*)(xbu + (long)i*64))[h];
  uint4 b = ((const uint4*)(xbu + (long)j*64))[h];
  float p = 0.f;
  float d;
  d = bl(a.x)-bl(b.x); p += d*d;  d = bh(a.x)-bh(b.x); p += d*d;
  d = bl(a.y)-bl(b.y); p += d*d;  d = bh(a.y)-bh(b.y); p += d*d;
  d = bl(a.z)-bl(b.z); p += d*d;  d = bh(a.z)-bh(b.z); p += d*d;
  d = bl(a.w)-bl(b.w); p += d*d;  d = bh(a.w)-bh(b.w); p += d*d;
  #pragma unroll
  for (int m = 1; m < 16; m <<= 1) p += __shfl_xor(p, m, 64);
  if (h == 0) rq[w] = sqrtf(p);
}

// ---- pass 2: node aggregation, 4 waves per node, LDS combine ----
__global__ __launch_bounds__(256) void k_aggr(const unsigned* __restrict__ xbu, const float* __restrict__ posf_cur,
                                              const int* __restrict__ row_ptr, const int* __restrict__ sj,
                                              const float* __restrict__ rq,
                                              ushort_t* __restrict__ Ab, float* __restrict__ posf_next){
  __shared__ float lds[3][200];
  int n    = blockIdx.x;
  int wave = threadIdx.x >> 6, lane = threadIdx.x & 63;
  int beg = row_ptr[n], end = row_ptr[n+1];
  float sxj0 = 0.f, sxj1 = 0.f, ssoh = 0.f, spos = 0.f;
  float cc = (10.0f/63.0f) * (float)lane;
  int idx = beg + wave;
  for (; idx + 12 < end; idx += 16){
    int j0 = sj[idx], j1 = sj[idx+4], j2 = sj[idx+8], j3 = sj[idx+12];
    float r0 = rq[idx], r1 = rq[idx+4], r2 = rq[idx+8], r3 = rq[idx+12];
    unsigned u0 = xbu[(long)j0*64 + lane];
    unsigned u1 = xbu[(long)j1*64 + lane];
    unsigned u2 = xbu[(long)j2*64 + lane];
    unsigned u3 = xbu[(long)j3*64 + lane];
    sxj0 += (bl(u0) + bl(u1)) + (bl(u2) + bl(u3));
    sxj1 += (bh(u0) + bh(u1)) + (bh(u2) + bh(u3));
    float t0 = r0 - cc, t1 = r1 - cc, t2 = r2 - cc, t3 = r3 - cc;
    ssoh += __expf(-10.0f*t0*t0) + __expf(-10.0f*t1*t1)
          + __expf(-10.0f*t2*t2) + __expf(-10.0f*t3*t3);
    if (lane < 3) spos += (posf_cur[j0*3 + lane] + posf_cur[j1*3 + lane])
                        + (posf_cur[j2*3 + lane] + posf_cur[j3*3 + lane]);
  }
  for (; idx < end; idx += 4){
    int j0 = sj[idx];
    float r0 = rq[idx];
    unsigned u0 = xbu[(long)j0*64 + lane];
    sxj0 += bl(u0); sxj1 += bh(u0);
    float t0 = r0 - cc;
    ssoh += __expf(-10.0f*t0*t0);
    if (lane < 3) spos += posf_cur[j0*3 + lane];
  }
  if (wave != 0){
    lds[wave-1][2*lane]   = sxj0;
    lds[wave-1][2*lane+1] = sxj1;
    lds[wave-1][128+lane] = ssoh;
    if (lane < 3) lds[wave-1][192+lane] = spos;
  }
  __syncthreads();
  if (wave == 0){
    #pragma unroll
    for (int w = 0; w < 3; ++w){
      sxj0 += lds[w][2*lane];
      sxj1 += lds[w][2*lane+1];
      ssoh += lds[w][128+lane];
      if (lane < 3) spos += lds[w][192+lane];
    }
    unsigned xi = xbu[(long)n*64 + lane];
    float cf = (float)(end - beg);
    ushort_t* Ar = Ab + (long)n*KP;
    ((unsigned*)Ar)[lane]      = xi;                       // x segment (exact bf16 copy)
    ((ushort2*)Ar)[64 + lane]  = pack2(cf*bl(xi), cf*bh(xi));
    ((ushort2*)Ar)[128 + lane] = pack2(sxj0, sxj1);
    Ar[384 + lane] = f2bs(ssoh);
    if (lane < 3){
      float pi = posf_cur[n*3 + lane];
      posf_next[n*3 + lane] = pi + (cf*pi - spos) / fmaxf(cf, 1.f);
    }
  }
}

// ---- node GEMM via MFMA, no LDS ----
__global__ __launch_bounds__(256) void k_gemm(const ushort_t* __restrict__ A, const ushort_t* __restrict__ WcT,
                                              const float* __restrict__ bx, ushort_t* __restrict__ xb_next,
                                              const float* __restrict__ x_ori, float* __restrict__ out,
                                              int final_flag){
  int wave = threadIdx.x >> 6, lane = threadIdx.x & 63;
  int quad = lane >> 4, l16 = lane & 15;
  int mbase = blockIdx.x*32 + (wave & 1)*16;
  int nbase = (wave >> 1)*64;
  const ushort_t* Arow = A + (long)(mbase + l16)*KP + quad*8;
  const ushort_t* Wbase = WcT + (long)nbase*KP + quad*8;
  f32x4 acc[4] = {f32x4{0,0,0,0}, f32x4{0,0,0,0}, f32x4{0,0,0,0}, f32x4{0,0,0,0}};
  for (int k0 = 0; k0 < KP; k0 += 32){
    short8 av = *(const short8*)(Arow + k0);
    #pragma unroll
    for (int t = 0; t < 4; ++t){
      short8 bv = *(const short8*)(Wbase + (long)(t*16 + l16)*KP + k0);
      acc[t] = __builtin_amdgcn_mfma_f32_16x16x32_bf16(av, bv, acc[t], 0, 0, 0);
    }
  }
  #pragma unroll
  for (int t = 0; t < 4; ++t){
    int col = nbase + t*16 + l16;
    float bxc = bx[col];
    #pragma unroll
    for (int r = 0; r < 4; ++r){
      int row = mbase + quad*4 + r;
      if (row < NN){
        float v = leaky(acc[t][r] + bxc);
        if (final_flag){
          out[(long)row*HD + col] = leaky(x_ori[(long)row*HD + col] + v);
        } else {
          xb_next[(long)row*HD + col] = f2bs(v);
        }
      }
    }
  }
}

extern "C" void kernel_launch(void* const* d_in, const int* in_sizes, int n_in,
                              void* d_out, int out_size, void* d_ws, size_t ws_size,
                              hipStream_t stream){
  const float* x   = (const float*)d_in[0];
  const float* pos = (const float*)d_in[1];
  const int*   ei  = (const int*)d_in[2];
  const float* ea  = (const float*)d_in[3];
  const float* Wm  = (const float*)d_in[4];
  const float* bm  = (const float*)d_in[5];
  const float* Wx  = (const float*)d_in[8];
  const float* bx  = (const float*)d_in[9];
  float* out_x   = (float*)d_out;
  float* out_pos = out_x + NN*HD;

  ushort_t* xbA    = (ushort_t*)d_ws;
  ushort_t* xbB    = xbA + NN*HD;
  ushort_t* Ab     = xbB + NN*HD;
  ushort_t* WcT    = Ab + (long)AROWS*KP;
  float*    pfA    = (float*)(WcT + 4*HD*KP);
  float*    pfB    = pfA + NN*3;
  float*    rq     = pfB + NN*3;
  int*      cnt    = (int*)(rq + NE);
  int*      c2     = cnt + NN;
  int*      row_ptr= c2 + NN;
  int*      si     = row_ptr + (NN+1);
  int*      sj     = si + NE;
  int*      se     = sj + NE;
  const int* ii = ei;
  const int* jj = ei + NE;

  hipMemsetAsync(cnt, 0, 2*NN*sizeof(int), stream);
  hipMemsetAsync(WcT, 0, (size_t)4*HD*KP*sizeof(ushort_t), stream);
  k_seed  <<<(NN*HD + 255)/256, 256, 0, stream>>>(x, xbA);
  k_count <<<(NE+255)/256, 256, 0, stream>>>(ii, cnt);
  k_scan  <<<1, 256, 0, stream>>>(cnt, row_ptr);
  k_fill  <<<(NE+255)/256, 256, 0, stream>>>(ii, jj, row_ptr, c2, si, sj, se);
  k_wc_top<<<(4*HD*HD)/256, 256, 0, stream>>>(Wx, WcT);
  k_wc_bot<<<dim3(11, 4), 256, 0, stream>>>(Wm, bm, Wx, WcT);
  k_prep  <<<NN/4, 256, 0, stream>>>(row_ptr, se, ea, Ab);

  ushort_t*    xs[4] = {xbA, xbB, xbA, xbB};
  ushort_t*    xd[4] = {xbB, xbA, xbB, xbA};   // xd[3] unused (final path writes out)
  const float* ps[4] = {pos, pfA, pfB, pfA};
  float*       pd[4] = {pfA, pfB, pfA, out_pos};

  for (int l = 0; l < 4; ++l){
    k_dist<<<(NE*16 + 255)/256, 256, 0, stream>>>((const unsigned*)xs[l], si, sj, rq);
    k_aggr<<<NN, 256, 0, stream>>>((const unsigned*)xs[l], ps[l], row_ptr, sj, rq, Ab, pd[l]);
    k_gemm<<<(NN+31)/32, 256, 0, stream>>>(Ab, WcT + (long)l*HD*KP, bx + l*HD,
                                           xd[l], x, out_x, l == 3 ? 1 : 0);
  }
}

// Round 6
// 371.700 us; speedup vs baseline: 2.1755x; 1.0671x over previous
//
#include <hip/hip_runtime.h>
#include <hip/hip_bf16.h>

#define NN 10000      // nodes
#define NE 320000     // edges
#define HD 128        // h_dim
#define ED 16         // e_dim
#define HID 256       // hid_dim
#define KP 480        // A row: [x 128 | cnt*x 128 | sum_xj 128 | sum_soh 64 | sum_ea 16 | cnt 1 | pad 15]
#define AROWS 10048

typedef unsigned short ushort_t;
typedef __attribute__((ext_vector_type(8))) short short8;
typedef __attribute__((ext_vector_type(4))) float f32x4;

__device__ __forceinline__ float leaky(float v){ return v > 0.f ? v : 0.01f*v; }
__device__ __forceinline__ ushort_t f2bs(float v){
  __hip_bfloat16 b = __float2bfloat16(v);
  return *(ushort_t*)&b;
}
__device__ __forceinline__ unsigned pack2u(float a, float b){
  return (unsigned)f2bs(a) | ((unsigned)f2bs(b) << 16);
}
__device__ __forceinline__ float bl(unsigned u){ return __uint_as_float(u << 16); }
__device__ __forceinline__ float bh(unsigned u){ return __uint_as_float(u & 0xffff0000u); }
__device__ __forceinline__ float2 cvt2(unsigned u){ return make_float2(bl(u), bh(u)); }

// ---- merged setup: seed x->bf16 | count | wc_top transpose ----
__global__ __launch_bounds__(256) void k_misc(const float* __restrict__ x, ushort_t* __restrict__ xb,
                                              const int* __restrict__ ii, int* __restrict__ cnt,
                                              const float* __restrict__ Wx, ushort_t* __restrict__ WcT){
  int t = blockIdx.x*256 + threadIdx.x;
  if (t < NN*HD){
    xb[t] = f2bs(x[t]);
  } else if (t < NN*HD + NE){
    atomicAdd(&cnt[ii[t - NN*HD]], 1);
  } else {
    int u = t - NN*HD - NE;
    if (u < 4*HD*HD){
      int l = u >> 14, r = (u >> 7) & 127, c = u & 127;
      WcT[((long)l*HD + c)*KP + r] = f2bs(Wx[(long)l*(HD+HID)*HD + r*HD + c]);
    }
  }
}

__global__ __launch_bounds__(256) void k_scan(const int* __restrict__ cnt, int* __restrict__ row_ptr){
  const int PER = 40;
  __shared__ int sh[256];
  int t = threadIdx.x;
  int base = t*PER;
  int s = 0;
  for (int k = 0; k < PER; ++k){ int idx = base+k; if (idx < NN) s += cnt[idx]; }
  sh[t] = s; __syncthreads();
  for (int off = 1; off < 256; off <<= 1){
    int v = (t >= off) ? sh[t-off] : 0;
    __syncthreads();
    sh[t] += v;
    __syncthreads();
  }
  int pre = sh[t] - s;
  for (int k = 0; k < PER; ++k){
    int idx = base+k;
    if (idx < NN){ row_ptr[idx] = pre; pre += cnt[idx]; }
  }
  if (t == 255) row_ptr[NN] = sh[255];
}

// fill CSR: sj + edge_attr rows scattered into CSR order (eas)
__global__ __launch_bounds__(256) void k_fill(const int* __restrict__ ii, const int* __restrict__ jj,
                                              const int* __restrict__ row_ptr, int* __restrict__ c2,
                                              int* __restrict__ sj, const float* __restrict__ ea,
                                              float* __restrict__ eas){
  int e = blockIdx.x*256 + threadIdx.x;
  if (e < NE){
    int a = ii[e];
    int p = atomicAdd(&c2[a], 1);
    int idx = row_ptr[a] + p;
    sj[idx] = jj[e];
    const float4* s = (const float4*)(ea + (long)e*ED);
    float4* d = (float4*)(eas + (long)idx*ED);
    d[0] = s[0]; d[1] = s[1]; d[2] = s[2]; d[3] = s[3];
  }
}

// ---- combined weights bottom: rows 128..464 of WcT = ([Wm;bm] @ Wx_bot)^T ----
__global__ __launch_bounds__(256) void k_wc_bot(const float* __restrict__ Wm, const float* __restrict__ bm,
                                                const float* __restrict__ Wx, ushort_t* __restrict__ WcT){
  __shared__ float a_s[16*36];
  __shared__ float w_s[16*128];
  int t  = threadIdx.x;
  int rb = blockIdx.x * 32;
  int l  = blockIdx.y;
  int lr = t >> 4, lk = t & 15;
  int wcc = t & 127, wk = t >> 7;
  int cg = t & 31, rg = t >> 5;
  const float* Wxb = Wx + (long)l*(HD+HID)*HD + HD*HD;
  float acc[4][4];
  #pragma unroll
  for (int i = 0; i < 4; ++i)
    #pragma unroll
    for (int j = 0; j < 4; ++j) acc[i][j] = 0.f;
  for (int k0 = 0; k0 < HID; k0 += 16){
    int m0 = rb + lr, m1 = rb + lr + 16;
    float v0 = 0.f, v1 = 0.f;
    if (m0 < 336) v0 = Wm[((long)l*336 + m0)*HID + k0 + lk];
    else if (m0 == 336) v0 = bm[l*HID + k0 + lk];
    if (m1 < 336) v1 = Wm[((long)l*336 + m1)*HID + k0 + lk];
    else if (m1 == 336) v1 = bm[l*HID + k0 + lk];
    a_s[lk*36 + lr]      = v0;
    a_s[lk*36 + lr + 16] = v1;
    #pragma unroll
    for (int q = 0; q < 8; ++q)
      w_s[(wk + 2*q)*128 + wcc] = Wxb[(k0 + wk + 2*q)*HD + wcc];
    __syncthreads();
    #pragma unroll
    for (int k = 0; k < 16; ++k){
      float4 av = *(const float4*)&a_s[k*36 + rg*4];
      float4 wv = *(const float4*)&w_s[k*128 + cg*4];
      acc[0][0] += av.x*wv.x; acc[0][1] += av.x*wv.y; acc[0][2] += av.x*wv.z; acc[0][3] += av.x*wv.w;
      acc[1][0] += av.y*wv.x; acc[1][1] += av.y*wv.y; acc[1][2] += av.y*wv.z; acc[1][3] += av.y*wv.w;
      acc[2][0] += av.z*wv.x; acc[2][1] += av.z*wv.y; acc[2][2] += av.z*wv.z; acc[2][3] += av.z*wv.w;
      acc[3][0] += av.w*wv.x; acc[3][1] += av.w*wv.y; acc[3][2] += av.w*wv.z; acc[3][3] += av.w*wv.w;
    }
    __syncthreads();
  }
  #pragma unroll
  for (int i = 0; i < 4; ++i){
    int m = rb + rg*4 + i;
    if (m < 337){
      #pragma unroll
      for (int j = 0; j < 4; ++j)
        WcT[((long)l*HD + cg*4 + j)*KP + 128 + m] = f2bs(acc[i][j]);
    }
  }
}

// ---- once per call: layer-invariant A segments (sum_ea from CSR-ordered eas, cnt) ----
__global__ __launch_bounds__(256) void k_prep(const int* __restrict__ row_ptr, const float* __restrict__ eas,
                                              ushort_t* __restrict__ Ab){
  int n    = blockIdx.x*4 + (threadIdx.x >> 6);
  int lane = threadIdx.x & 63;
  int beg = row_ptr[n], end = row_ptr[n+1];
  int q = lane >> 4, c = lane & 15;
  float acc = 0.f;
  for (int it = beg + q; it < end; it += 4)
    acc += eas[(long)it*ED + c];
  acc += __shfl_xor(acc, 16, 64);
  acc += __shfl_xor(acc, 32, 64);
  ushort_t* Ar = Ab + (long)n*KP;
  if (lane < 16) Ar[448 + lane] = f2bs(acc);
  if (lane < 16) Ar[464 + lane] = (lane == 0) ? f2bs((float)(end - beg)) : (ushort_t)0;
}

// ---- per-layer fused edge kernel: dist + aggregation ----
// 16 lanes per node-half (lane holds 8 dims as uint4); 2 halves/node; 8 nodes/block
__global__ __launch_bounds__(256) void k_edge(const uint4* __restrict__ xb4, const float* __restrict__ posf_cur,
                                              const int* __restrict__ row_ptr, const int* __restrict__ sj,
                                              ushort_t* __restrict__ Ab, float* __restrict__ posf_next){
  int tid = threadIdx.x;
  int n   = blockIdx.x*8 + (tid >> 5);
  int sub = tid & 31;
  int g   = sub >> 4;          // which half of the edge list
  int gl  = sub & 15;          // lane within node group
  int beg = row_ptr[n], end = row_ptr[n+1];
  int len = end - beg;
  int q0 = beg + ((len * g) >> 1);
  int q1 = beg + ((len * (g+1)) >> 1);

  uint4 xi = xb4[(long)n*16 + gl];
  float2 xi0 = cvt2(xi.x), xi1 = cvt2(xi.y), xi2 = cvt2(xi.z), xi3 = cvt2(xi.w);
  float c0 = (10.0f/63.0f)*(float)(4*gl);
  float c1 = (10.0f/63.0f)*(float)(4*gl+1);
  float c2 = (10.0f/63.0f)*(float)(4*gl+2);
  float c3 = (10.0f/63.0f)*(float)(4*gl+3);

  float2 s0 = {0,0}, s1 = {0,0}, s2 = {0,0}, s3 = {0,0};
  float h0 = 0, h1 = 0, h2 = 0, h3 = 0, sp = 0;

#define EPROC(Bv, Jv) { \
    float2 e0=cvt2(Bv.x), e1=cvt2(Bv.y), e2=cvt2(Bv.z), e3=cvt2(Bv.w); \
    float d, p=0.f; \
    d=xi0.x-e0.x; p+=d*d;  d=xi0.y-e0.y; p+=d*d; \
    d=xi1.x-e1.x; p+=d*d;  d=xi1.y-e1.y; p+=d*d; \
    d=xi2.x-e2.x; p+=d*d;  d=xi2.y-e2.y; p+=d*d; \
    d=xi3.x-e3.x; p+=d*d;  d=xi3.y-e3.y; p+=d*d; \
    p += __shfl_xor(p,1,64); p += __shfl_xor(p,2,64); \
    p += __shfl_xor(p,4,64); p += __shfl_xor(p,8,64); \
    float r = sqrtf(p); \
    float t0=r-c0, t1=r-c1, t2=r-c2, t3=r-c3; \
    h0 += __expf(-10.f*t0*t0); h1 += __expf(-10.f*t1*t1); \
    h2 += __expf(-10.f*t2*t2); h3 += __expf(-10.f*t3*t3); \
    s0.x+=e0.x; s0.y+=e0.y; s1.x+=e1.x; s1.y+=e1.y; \
    s2.x+=e2.x; s2.y+=e2.y; s3.x+=e3.x; s3.y+=e3.y; \
    if (gl < 3) sp += posf_cur[(long)Jv*3 + gl]; }

  int idx = q0;
  for (; idx + 3 < q1; idx += 4){
    int j0 = sj[idx], j1 = sj[idx+1], j2 = sj[idx+2], j3 = sj[idx+3];
    uint4 B0 = xb4[(long)j0*16 + gl];
    uint4 B1 = xb4[(long)j1*16 + gl];
    uint4 B2 = xb4[(long)j2*16 + gl];
    uint4 B3 = xb4[(long)j3*16 + gl];
    EPROC(B0, j0); EPROC(B1, j1); EPROC(B2, j2); EPROC(B3, j3);
  }
  for (; idx < q1; ++idx){
    int j0 = sj[idx];
    uint4 B0 = xb4[(long)j0*16 + gl];
    EPROC(B0, j0);
  }
#undef EPROC

  // combine the two halves (xor 16 swaps g0<->g1 within each 32-lane pair)
  s0.x += __shfl_xor(s0.x,16,64); s0.y += __shfl_xor(s0.y,16,64);
  s1.x += __shfl_xor(s1.x,16,64); s1.y += __shfl_xor(s1.y,16,64);
  s2.x += __shfl_xor(s2.x,16,64); s2.y += __shfl_xor(s2.y,16,64);
  s3.x += __shfl_xor(s3.x,16,64); s3.y += __shfl_xor(s3.y,16,64);
  h0 += __shfl_xor(h0,16,64); h1 += __shfl_xor(h1,16,64);
  h2 += __shfl_xor(h2,16,64); h3 += __shfl_xor(h3,16,64);
  sp += __shfl_xor(sp,16,64);

  if (g == 0){
    float cf = (float)len;
    ushort_t* Ar = Ab + (long)n*KP;
    ((uint4*)Ar)[gl] = xi;
    uint4 w1 = make_uint4(pack2u(cf*xi0.x, cf*xi0.y), pack2u(cf*xi1.x, cf*xi1.y),
                          pack2u(cf*xi2.x, cf*xi2.y), pack2u(cf*xi3.x, cf*xi3.y));
    ((uint4*)(Ar + 128))[gl] = w1;
    uint4 w2 = make_uint4(pack2u(s0.x, s0.y), pack2u(s1.x, s1.y),
                          pack2u(s2.x, s2.y), pack2u(s3.x, s3.y));
    ((uint4*)(Ar + 256))[gl] = w2;
    uint2 w3 = make_uint2(pack2u(h0, h1), pack2u(h2, h3));
    ((uint2*)(Ar + 384))[gl] = w3;
    if (gl < 3){
      float pi = posf_cur[n*3 + gl];
      posf_next[n*3 + gl] = pi + (cf*pi - sp) / fmaxf(cf, 1.f);
    }
  }
}

// ---- node GEMM via MFMA, no LDS ----
__global__ __launch_bounds__(256) void k_gemm(const ushort_t* __restrict__ A, const ushort_t* __restrict__ WcT,
                                              const float* __restrict__ bx, ushort_t* __restrict__ xb_next,
                                              const float* __restrict__ x_ori, float* __restrict__ out,
                                              int final_flag){
  int wave = threadIdx.x >> 6, lane = threadIdx.x & 63;
  int quad = lane >> 4, l16 = lane & 15;
  int mbase = blockIdx.x*32 + (wave & 1)*16;
  int nbase = (wave >> 1)*64;
  const ushort_t* Arow = A + (long)(mbase + l16)*KP + quad*8;
  const ushort_t* Wbase = WcT + (long)nbase*KP + quad*8;
  f32x4 acc[4] = {f32x4{0,0,0,0}, f32x4{0,0,0,0}, f32x4{0,0,0,0}, f32x4{0,0,0,0}};
  for (int k0 = 0; k0 < KP; k0 += 32){
    short8 av = *(const short8*)(Arow + k0);
    #pragma unroll
    for (int t = 0; t < 4; ++t){
      short8 bv = *(const short8*)(Wbase + (long)(t*16 + l16)*KP + k0);
      acc[t] = __builtin_amdgcn_mfma_f32_16x16x32_bf16(av, bv, acc[t], 0, 0, 0);
    }
  }
  #pragma unroll
  for (int t = 0; t < 4; ++t){
    int col = nbase + t*16 + l16;
    float bxc = bx[col];
    #pragma unroll
    for (int r = 0; r < 4; ++r){
      int row = mbase + quad*4 + r;
      if (row < NN){
        float v = leaky(acc[t][r] + bxc);
        if (final_flag){
          out[(long)row*HD + col] = leaky(x_ori[(long)row*HD + col] + v);
        } else {
          xb_next[(long)row*HD + col] = f2bs(v);
        }
      }
    }
  }
}

extern "C" void kernel_launch(void* const* d_in, const int* in_sizes, int n_in,
                              void* d_out, int out_size, void* d_ws, size_t ws_size,
                              hipStream_t stream){
  const float* x   = (const float*)d_in[0];
  const float* pos = (const float*)d_in[1];
  const int*   ei  = (const int*)d_in[2];
  const float* ea  = (const float*)d_in[3];
  const float* Wm  = (const float*)d_in[4];
  const float* bm  = (const float*)d_in[5];
  const float* Wx  = (const float*)d_in[8];
  const float* bx  = (const float*)d_in[9];
  float* out_x   = (float*)d_out;
  float* out_pos = out_x + NN*HD;

  ushort_t* xbA    = (ushort_t*)d_ws;
  ushort_t* xbB    = xbA + NN*HD;
  ushort_t* Ab     = xbB + NN*HD;
  ushort_t* WcT    = Ab + (long)AROWS*KP;
  float*    pfA    = (float*)(WcT + 4*HD*KP);
  float*    pfB    = pfA + NN*3;
  float*    eas    = pfB + NN*3;
  int*      cnt    = (int*)(eas + (long)NE*ED);
  int*      c2     = cnt + NN;
  int*      row_ptr= c2 + NN;
  int*      sj     = row_ptr + (NN+1);
  const int* ii = ei;
  const int* jj = ei + NE;

  hipMemsetAsync(cnt, 0, 2*NN*sizeof(int), stream);
  hipMemsetAsync(WcT, 0, (size_t)4*HD*KP*sizeof(ushort_t), stream);
  k_misc  <<<(NN*HD + NE + 4*HD*HD + 255)/256, 256, 0, stream>>>(x, xbA, ii, cnt, Wx, WcT);
  k_scan  <<<1, 256, 0, stream>>>(cnt, row_ptr);
  k_fill  <<<(NE+255)/256, 256, 0, stream>>>(ii, jj, row_ptr, c2, sj, ea, eas);
  k_wc_bot<<<dim3(11, 4), 256, 0, stream>>>(Wm, bm, Wx, WcT);
  k_prep  <<<NN/4, 256, 0, stream>>>(row_ptr, eas, Ab);

  ushort_t*    xs[4] = {xbA, xbB, xbA, xbB};
  ushort_t*    xd[4] = {xbB, xbA, xbB, xbA};   // xd[3] unused (final path writes out)
  const float* ps[4] = {pos, pfA, pfB, pfA};
  float*       pd[4] = {pfA, pfB, pfA, out_pos};

  for (int l = 0; l < 4; ++l){
    k_edge<<<NN/8, 256, 0, stream>>>((const uint4*)xs[l], ps[l], row_ptr, sj, Ab, pd[l]);
    k_gemm<<<(NN+31)/32, 256, 0, stream>>>(Ab, WcT + (long)l*HD*KP, bx + l*HD,
                                           xd[l], x, out_x, l == 3 ? 1 : 0);
  }
}

// Round 7
// 334.711 us; speedup vs baseline: 2.4159x; 1.1105x over previous
//
#include <hip/hip_runtime.h>
#include <hip/hip_bf16.h>

#define NN 10000      // nodes
#define NE 320000     // edges
#define HD 128        // h_dim
#define ED 16         // e_dim
#define HID 256       // hid_dim
#define KP 480        // A row: [x 128 | cnt*x 128 | sum_xj 128 | sum_soh 64 | sum_ea 16 | cnt 1 | pad 15]
#define AST 488       // LDS A-row stride (ushorts), 976B = 16B-aligned

typedef unsigned short ushort_t;
typedef __attribute__((ext_vector_type(8))) short short8;
typedef __attribute__((ext_vector_type(4))) float f32x4;

__device__ __forceinline__ float leaky(float v){ return v > 0.f ? v : 0.01f*v; }
__device__ __forceinline__ ushort_t f2bs(float v){
  __hip_bfloat16 b = __float2bfloat16(v);
  return *(ushort_t*)&b;
}
__device__ __forceinline__ unsigned pack2u(float a, float b){
  return (unsigned)f2bs(a) | ((unsigned)f2bs(b) << 16);
}
__device__ __forceinline__ float bl(unsigned u){ return __uint_as_float(u << 16); }
__device__ __forceinline__ float bh(unsigned u){ return __uint_as_float(u & 0xffff0000u); }
__device__ __forceinline__ float2 cvt2(unsigned u){ return make_float2(bl(u), bh(u)); }

// ---- merged setup: seed x->bf16 | edge count | wc_top transpose | WcT K-pad zeros ----
__global__ __launch_bounds__(256) void k_misc(const float* __restrict__ x, ushort_t* __restrict__ xb,
                                              const int* __restrict__ ii, int* __restrict__ cnt,
                                              const float* __restrict__ Wx, ushort_t* __restrict__ WcT){
  int t = blockIdx.x*256 + threadIdx.x;
  if (t < NN*HD){
    xb[t] = f2bs(x[t]);
  } else if (t < NN*HD + NE){
    atomicAdd(&cnt[ii[t - NN*HD]], 1);
  } else if (t < NN*HD + NE + 4*HD*HD){
    int u = t - NN*HD - NE;
    int l = u >> 14, r = (u >> 7) & 127, c = u & 127;
    WcT[((long)l*HD + c)*KP + r] = f2bs(Wx[(long)l*(HD+HID)*HD + r*HD + c]);
  } else {
    int u = t - NN*HD - NE - 4*HD*HD;     // 512 rows x 15 pad cols
    if (u < 4*HD*15){
      int row = u / 15, k = 465 + u % 15;
      WcT[(long)row*KP + k] = 0;
    }
  }
}

__global__ __launch_bounds__(256) void k_scan(const int* __restrict__ cnt, int* __restrict__ row_ptr){
  const int PER = 40;
  __shared__ int sh[256];
  int t = threadIdx.x;
  int base = t*PER;
  int s = 0;
  for (int k = 0; k < PER; ++k){ int idx = base+k; if (idx < NN) s += cnt[idx]; }
  sh[t] = s; __syncthreads();
  for (int off = 1; off < 256; off <<= 1){
    int v = (t >= off) ? sh[t-off] : 0;
    __syncthreads();
    sh[t] += v;
    __syncthreads();
  }
  int pre = sh[t] - s;
  for (int k = 0; k < PER; ++k){
    int idx = base+k;
    if (idx < NN){ row_ptr[idx] = pre; pre += cnt[idx]; }
  }
  if (t == 255) row_ptr[NN] = sh[255];
}

// ---- merged: CSR fill (blocks 0..1249) | wc_bot GEMM (blocks 1250..1293) ----
__global__ __launch_bounds__(256) void k_fillwc(const int* __restrict__ ii, const int* __restrict__ jj,
                                                const int* __restrict__ row_ptr, int* __restrict__ c2,
                                                int* __restrict__ sj, int* __restrict__ se,
                                                const float* __restrict__ Wm, const float* __restrict__ bm,
                                                const float* __restrict__ Wx, ushort_t* __restrict__ WcT){
  if (blockIdx.x < 1250){
    int e = blockIdx.x*256 + threadIdx.x;   // 1250*256 == NE exactly
    int a = ii[e];
    int p = atomicAdd(&c2[a], 1);
    int idx = row_ptr[a] + p;
    sj[idx] = jj[e];
    se[idx] = e;
    return;
  }
  __shared__ float a_s[16*36];
  __shared__ float w_s[16*128];
  int bi = blockIdx.x - 1250;
  int t  = threadIdx.x;
  int rb = (bi % 11) * 32;
  int l  = bi / 11;
  int lr = t >> 4, lk = t & 15;
  int wcc = t & 127, wk = t >> 7;
  int cg = t & 31, rg = t >> 5;
  const float* Wxb = Wx + (long)l*(HD+HID)*HD + HD*HD;
  float acc[4][4];
  #pragma unroll
  for (int i = 0; i < 4; ++i)
    #pragma unroll
    for (int j = 0; j < 4; ++j) acc[i][j] = 0.f;
  for (int k0 = 0; k0 < HID; k0 += 16){
    int m0 = rb + lr, m1 = rb + lr + 16;
    float v0 = 0.f, v1 = 0.f;
    if (m0 < 336) v0 = Wm[((long)l*336 + m0)*HID + k0 + lk];
    else if (m0 == 336) v0 = bm[l*HID + k0 + lk];
    if (m1 < 336) v1 = Wm[((long)l*336 + m1)*HID + k0 + lk];
    else if (m1 == 336) v1 = bm[l*HID + k0 + lk];
    a_s[lk*36 + lr]      = v0;
    a_s[lk*36 + lr + 16] = v1;
    #pragma unroll
    for (int q = 0; q < 8; ++q)
      w_s[(wk + 2*q)*128 + wcc] = Wxb[(k0 + wk + 2*q)*HD + wcc];
    __syncthreads();
    #pragma unroll
    for (int k = 0; k < 16; ++k){
      float4 av = *(const float4*)&a_s[k*36 + rg*4];
      float4 wv = *(const float4*)&w_s[k*128 + cg*4];
      acc[0][0] += av.x*wv.x; acc[0][1] += av.x*wv.y; acc[0][2] += av.x*wv.z; acc[0][3] += av.x*wv.w;
      acc[1][0] += av.y*wv.x; acc[1][1] += av.y*wv.y; acc[1][2] += av.y*wv.z; acc[1][3] += av.y*wv.w;
      acc[2][0] += av.z*wv.x; acc[2][1] += av.z*wv.y; acc[2][2] += av.z*wv.z; acc[2][3] += av.z*wv.w;
      acc[3][0] += av.w*wv.x; acc[3][1] += av.w*wv.y; acc[3][2] += av.w*wv.z; acc[3][3] += av.w*wv.w;
    }
    __syncthreads();
  }
  #pragma unroll
  for (int i = 0; i < 4; ++i){
    int m = rb + rg*4 + i;
    if (m < 337){
      #pragma unroll
      for (int j = 0; j < 4; ++j)
        WcT[((long)l*HD + cg*4 + j)*KP + 128 + m] = f2bs(acc[i][j]);
    }
  }
}

// ---- fused per-layer kernel: edge aggregation (-> LDS A tile) + MFMA GEMM ----
// 1250 blocks x 256 thr; 8 nodes/block; 16 lanes per node-half
template<int FIRST, int FINAL>
__global__ __launch_bounds__(256) void k_layer(const uint4* __restrict__ xb4, const float* __restrict__ posf_cur,
                                               const int* __restrict__ row_ptr, const int* __restrict__ sj,
                                               const int* __restrict__ se, const float* __restrict__ ea,
                                               ushort_t* __restrict__ inv,
                                               const ushort_t* __restrict__ WcT, const float* __restrict__ bx,
                                               ushort_t* __restrict__ xb_next, const float* __restrict__ x_ori,
                                               float* __restrict__ out, float* __restrict__ posf_next){
  __shared__ ushort_t Asm[8*AST];
  int tid = threadIdx.x;
  int nl  = tid >> 5;                       // node-local 0..7
  int n   = blockIdx.x*8 + nl;
  int sub = tid & 31;
  int g   = sub >> 4;                       // half of edge list
  int gl  = sub & 15;                       // lane in group
  int beg = row_ptr[n], end = row_ptr[n+1];
  int len = end - beg;
  int q0 = beg + ((len * g) >> 1);
  int q1 = beg + ((len * (g+1)) >> 1);

  uint4 xi = xb4[(long)n*16 + gl];
  float2 xi0 = cvt2(xi.x), xi1 = cvt2(xi.y), xi2 = cvt2(xi.z), xi3 = cvt2(xi.w);
  float c0 = (10.0f/63.0f)*(float)(4*gl);
  float c1 = (10.0f/63.0f)*(float)(4*gl+1);
  float c2 = (10.0f/63.0f)*(float)(4*gl+2);
  float c3 = (10.0f/63.0f)*(float)(4*gl+3);

  float2 s0 = {0,0}, s1 = {0,0}, s2 = {0,0}, s3 = {0,0};
  float h0 = 0, h1 = 0, h2 = 0, h3 = 0, sp = 0, sea = 0;

#define EPROC(Bv, Jv, Ev) { \
    float2 e0=cvt2(Bv.x), e1=cvt2(Bv.y), e2=cvt2(Bv.z), e3=cvt2(Bv.w); \
    float d, p=0.f; \
    d=xi0.x-e0.x; p+=d*d;  d=xi0.y-e0.y; p+=d*d; \
    d=xi1.x-e1.x; p+=d*d;  d=xi1.y-e1.y; p+=d*d; \
    d=xi2.x-e2.x; p+=d*d;  d=xi2.y-e2.y; p+=d*d; \
    d=xi3.x-e3.x; p+=d*d;  d=xi3.y-e3.y; p+=d*d; \
    p += __shfl_xor(p,1,64); p += __shfl_xor(p,2,64); \
    p += __shfl_xor(p,4,64); p += __shfl_xor(p,8,64); \
    float r = sqrtf(p); \
    float t0=r-c0, t1=r-c1, t2=r-c2, t3=r-c3; \
    h0 += __expf(-10.f*t0*t0); h1 += __expf(-10.f*t1*t1); \
    h2 += __expf(-10.f*t2*t2); h3 += __expf(-10.f*t3*t3); \
    s0.x+=e0.x; s0.y+=e0.y; s1.x+=e1.x; s1.y+=e1.y; \
    s2.x+=e2.x; s2.y+=e2.y; s3.x+=e3.x; s3.y+=e3.y; \
    if (FIRST) sea += ea[(long)(Ev)*ED + gl]; \
    if (gl < 3) sp += posf_cur[(long)Jv*3 + gl]; }

  int idx = q0;
  for (; idx + 3 < q1; idx += 4){
    int j0 = sj[idx], j1 = sj[idx+1], j2 = sj[idx+2], j3 = sj[idx+3];
    int e0i = FIRST ? se[idx]   : 0;
    int e1i = FIRST ? se[idx+1] : 0;
    int e2i = FIRST ? se[idx+2] : 0;
    int e3i = FIRST ? se[idx+3] : 0;
    uint4 B0 = xb4[(long)j0*16 + gl];
    uint4 B1 = xb4[(long)j1*16 + gl];
    uint4 B2 = xb4[(long)j2*16 + gl];
    uint4 B3 = xb4[(long)j3*16 + gl];
    EPROC(B0, j0, e0i); EPROC(B1, j1, e1i); EPROC(B2, j2, e2i); EPROC(B3, j3, e3i);
  }
  for (; idx < q1; ++idx){
    int j0 = sj[idx];
    int e0i = FIRST ? se[idx] : 0;
    uint4 B0 = xb4[(long)j0*16 + gl];
    EPROC(B0, j0, e0i);
  }
#undef EPROC

  // combine halves (xor 16 swaps g0<->g1 within each 32-lane pair)
  s0.x += __shfl_xor(s0.x,16,64); s0.y += __shfl_xor(s0.y,16,64);
  s1.x += __shfl_xor(s1.x,16,64); s1.y += __shfl_xor(s1.y,16,64);
  s2.x += __shfl_xor(s2.x,16,64); s2.y += __shfl_xor(s2.y,16,64);
  s3.x += __shfl_xor(s3.x,16,64); s3.y += __shfl_xor(s3.y,16,64);
  h0 += __shfl_xor(h0,16,64); h1 += __shfl_xor(h1,16,64);
  h2 += __shfl_xor(h2,16,64); h3 += __shfl_xor(h3,16,64);
  sp += __shfl_xor(sp,16,64);
  if (FIRST) sea += __shfl_xor(sea,16,64);

  if (g == 0){
    float cf = (float)len;
    ushort_t* Ar = Asm + nl*AST;
    ((uint4*)Ar)[gl] = xi;
    ((uint4*)(Ar + 128))[gl] = make_uint4(pack2u(cf*xi0.x, cf*xi0.y), pack2u(cf*xi1.x, cf*xi1.y),
                                          pack2u(cf*xi2.x, cf*xi2.y), pack2u(cf*xi3.x, cf*xi3.y));
    ((uint4*)(Ar + 256))[gl] = make_uint4(pack2u(s0.x, s0.y), pack2u(s1.x, s1.y),
                                          pack2u(s2.x, s2.y), pack2u(s3.x, s3.y));
    ((uint2*)(Ar + 384))[gl] = make_uint2(pack2u(h0, h1), pack2u(h2, h3));
    ushort_t sea_us;
    if (FIRST){
      sea_us = f2bs(sea);
      inv[(long)n*16 + gl] = sea_us;
    } else {
      sea_us = inv[(long)n*16 + gl];
    }
    Ar[448 + gl] = sea_us;
    Ar[464 + gl] = (gl == 0) ? f2bs(cf) : (ushort_t)0;
    if (gl < 3){
      float pi = posf_cur[n*3 + gl];
      posf_next[n*3 + gl] = pi + (cf*pi - sp) / fmaxf(cf, 1.f);
    }
  }
  __syncthreads();

  // ---- phase B: MFMA GEMM, M=16 tile (top 8 rows real), cols = wave*32..+32 ----
  int wave = tid >> 6, lane = tid & 63;
  int quad = lane >> 4, l16 = lane & 15;
  int nb = wave * 32;
  const ushort_t* Arow = Asm + (l16 & 7)*AST + quad*8;
  const ushort_t* W0 = WcT + (long)(nb + l16)*KP + quad*8;
  const ushort_t* W1 = WcT + (long)(nb + 16 + l16)*KP + quad*8;
  f32x4 acc0 = {0,0,0,0}, acc1 = {0,0,0,0};
  for (int k0 = 0; k0 < KP; k0 += 32){
    short8 av = *(const short8*)(Arow + k0);
    short8 b0 = *(const short8*)(W0 + k0);
    short8 b1 = *(const short8*)(W1 + k0);
    acc0 = __builtin_amdgcn_mfma_f32_16x16x32_bf16(av, b0, acc0, 0, 0, 0);
    acc1 = __builtin_amdgcn_mfma_f32_16x16x32_bf16(av, b1, acc1, 0, 0, 0);
  }
  float bx0 = bx[nb + l16], bx1 = bx[nb + 16 + l16];
  #pragma unroll
  for (int r = 0; r < 4; ++r){
    int row = quad*4 + r;
    if (row < 8){
      long base = (long)(blockIdx.x*8 + row)*HD;
      float v0 = leaky(acc0[r] + bx0);
      float v1 = leaky(acc1[r] + bx1);
      if (FINAL){
        out[base + nb + l16]      = leaky(x_ori[base + nb + l16] + v0);
        out[base + nb + 16 + l16] = leaky(x_ori[base + nb + 16 + l16] + v1);
      } else {
        xb_next[base + nb + l16]      = f2bs(v0);
        xb_next[base + nb + 16 + l16] = f2bs(v1);
      }
    }
  }
}

extern "C" void kernel_launch(void* const* d_in, const int* in_sizes, int n_in,
                              void* d_out, int out_size, void* d_ws, size_t ws_size,
                              hipStream_t stream){
  const float* x   = (const float*)d_in[0];
  const float* pos = (const float*)d_in[1];
  const int*   ei  = (const int*)d_in[2];
  const float* ea  = (const float*)d_in[3];
  const float* Wm  = (const float*)d_in[4];
  const float* bm  = (const float*)d_in[5];
  const float* Wx  = (const float*)d_in[8];
  const float* bx  = (const float*)d_in[9];
  float* out_x   = (float*)d_out;
  float* out_pos = out_x + NN*HD;

  ushort_t* xbA    = (ushort_t*)d_ws;
  ushort_t* xbB    = xbA + NN*HD;
  ushort_t* WcT    = xbB + NN*HD;
  ushort_t* inv    = WcT + 4*HD*KP;
  float*    pfA    = (float*)(inv + NN*16);
  float*    pfB    = pfA + NN*3;
  int*      cnt    = (int*)(pfB + NN*3);
  int*      c2     = cnt + NN;
  int*      row_ptr= c2 + NN;
  int*      sj     = row_ptr + (NN+1);
  int*      se     = sj + NE;
  const int* ii = ei;
  const int* jj = ei + NE;

  hipMemsetAsync(cnt, 0, 2*NN*sizeof(int), stream);
  int misc_threads = NN*HD + NE + 4*HD*HD + 4*HD*15;
  k_misc  <<<(misc_threads + 255)/256, 256, 0, stream>>>(x, xbA, ii, cnt, Wx, WcT);
  k_scan  <<<1, 256, 0, stream>>>(cnt, row_ptr);
  k_fillwc<<<1250 + 44, 256, 0, stream>>>(ii, jj, row_ptr, c2, sj, se, Wm, bm, Wx, WcT);

  const float* ps[4] = {pos, pfA, pfB, pfA};
  float*       pd[4] = {pfA, pfB, pfA, out_pos};

  k_layer<1,0><<<1250, 256, 0, stream>>>((const uint4*)xbA, ps[0], row_ptr, sj, se, ea, inv,
                                         WcT + 0*HD*KP, bx + 0*HD, xbB, x, out_x, pd[0]);
  k_layer<0,0><<<1250, 256, 0, stream>>>((const uint4*)xbB, ps[1], row_ptr, sj, se, ea, inv,
                                         WcT + 1*(long)HD*KP, bx + 1*HD, xbA, x, out_x, pd[1]);
  k_layer<0,0><<<1250, 256, 0, stream>>>((const uint4*)xbA, ps[2], row_ptr, sj, se, ea, inv,
                                         WcT + 2*(long)HD*KP, bx + 2*HD, xbB, x, out_x, pd[2]);
  k_layer<0,1><<<1250, 256, 0, stream>>>((const uint4*)xbB, ps[3], row_ptr, sj, se, ea, inv,
                                         WcT + 3*(long)HD*KP, bx + 3*HD, xbA, x, out_x, pd[3]);
}